// Round 18
// baseline (73796.387 us; speedup 1.0000x reference)
//
#include <hip/hip_runtime.h>

typedef unsigned short u16;
typedef __attribute__((ext_vector_type(4))) float f32x4;

__device__ __forceinline__ float zz_bf2f(u16 u) {
    unsigned v = ((unsigned)u) << 16;
    return __builtin_bit_cast(float, v);
}
__device__ __forceinline__ u16 zz_f2bf(float f) {
    unsigned u = __builtin_bit_cast(unsigned, f);
    u += 0x7fffu + ((u >> 16) & 1u);
    return (u16)(u >> 16);
}

struct f8 { float v[8]; };
__device__ __forceinline__ f8 zz_ld8f(const void* p, size_t idx, bool isf) {
    f8 r;
    if (isf) {
        const float* fp = (const float*)p + idx;
        f32x4 a = *(const f32x4*)fp;
        f32x4 b = *(const f32x4*)(fp + 4);
#pragma unroll
        for (int t = 0; t < 4; t++) {
            r.v[t] = a[t];
            r.v[4 + t] = b[t];
        }
    } else {
        const u16* up = (const u16*)p + idx;
#pragma unroll
        for (int t = 0; t < 8; t++) r.v[t] = zz_bf2f(up[t]);
    }
    return r;
}

__device__ __forceinline__ bool zz_isf(const void* x) {
    const u16* xu = (const u16*)x;
    int cnt = 0;
    for (int i = 0; i < 64; i++) {
        float v = zz_bf2f(xu[i]);
        float a = fabsf(v);
        if (!(a <= 1e8f) || (v != 0.f && a < 1e-8f)) cnt++;
    }
    return cnt >= 16;
}

// ---------------- projections: QZ/KZ/PZ rows for one (batch,head), bf16 ws ----------------
__global__ __launch_bounds__(256) void zk17_proj(const void* __restrict__ x, unsigned long long xOff,
                                                 const void* __restrict__ Qw, const void* __restrict__ Kw,
                                                 const void* __restrict__ Pw, unsigned long long wOff,
                                                 u16* __restrict__ QZ, u16* __restrict__ KZ,
                                                 u16* __restrict__ PZ) {
    const bool isf = zz_isf(x);
    const int part = blockIdx.y;
    const void* W = (part == 0) ? Qw : ((part == 1) ? Kw : Pw);
    u16* Out = (part == 0) ? QZ : ((part == 1) ? KZ : PZ);
    const int t = blockIdx.x;
    const int i0 = threadIdx.x;
    float acc0 = 0.f, acc1 = 0.f;
    for (int j = 0; j < 512; j += 8) {
        f8 xv = zz_ld8f(x, (size_t)xOff + (size_t)t * 512 + j, isf);
        f8 w0 = zz_ld8f(W, (size_t)wOff + (size_t)i0 * 512 + j, isf);
        f8 w1 = zz_ld8f(W, (size_t)wOff + (size_t)(i0 + 256) * 512 + j, isf);
#pragma unroll
        for (int u = 0; u < 8; u++) {
            acc0 += xv.v[u] * w0.v[u];
            acc1 += xv.v[u] * w1.v[u];
        }
    }
    Out[(size_t)t * 512 + i0] = zz_f2bf(acc0);
    Out[(size_t)t * 512 + i0 + 256] = zz_f2bf(acc1);
}

// ---------------- QK^T for row-chunk [t0, t0+CH) ----------------
__global__ __launch_bounds__(256) void zk17_qk(const u16* __restrict__ QZ, const u16* __restrict__ KZ,
                                               u16* __restrict__ Spc, int t0) {
    const int r = blockIdx.x;
    const int t = t0 + r;
    for (int s = threadIdx.x; s <= t; s += 256) {
        float acc = 0.f;
        for (int j = 0; j < 512; j++)
            acc += zz_bf2f(QZ[(size_t)t * 512 + j]) * zz_bf2f(KZ[(size_t)s * 512 + j]);
        Spc[(size_t)r * 2048 + s] = zz_f2bf(acc);
    }
}

// ---------------- causal row softmax on chunk, in place ----------------
__global__ __launch_bounds__(256) void zk17_sm(u16* __restrict__ Spc, int t0) {
    const int wid = threadIdx.x >> 6, lane = threadIdx.x & 63;
    const int r = blockIdx.x * 4 + wid;
    const int t = t0 + r;
    u16* rowp = Spc + (size_t)r * 2048 + lane * 32;
    const float SCL2 = 0.06375826722338107f;  // (1/sqrt(512)) * log2(e)
    float v[32];
    float mx = -INFINITY;
#pragma unroll
    for (int i = 0; i < 32; i++) {
        const int s = lane * 32 + i;
        v[i] = (s <= t) ? zz_bf2f(rowp[i]) * SCL2 : -INFINITY;
        mx = fmaxf(mx, v[i]);
    }
#pragma unroll
    for (int d = 1; d < 64; d <<= 1) mx = fmaxf(mx, __shfl_xor(mx, d));
    float p[32];
    float sum = 0.f;
#pragma unroll
    for (int i = 0; i < 32; i++) {
        p[i] = exp2f(v[i] - mx);
        sum += p[i];
    }
#pragma unroll
    for (int d = 1; d < 64; d <<= 1) sum += __shfl_xor(sum, d);
    const float inv = 1.f / sum;
#pragma unroll
    for (int i = 0; i < 32; i++) rowp[i] = zz_f2bf(p[i] * inv);
}

// ---------------- PV for chunk ----------------
__global__ __launch_bounds__(256) void zk17_pv(const u16* __restrict__ Spc, const u16* __restrict__ PZ,
                                               u16* __restrict__ Oc, int t0) {
    const int r = blockIdx.x;
    const int t = t0 + r;
    const int i0 = threadIdx.x;
    float acc0 = 0.f, acc1 = 0.f;
    for (int s = 0; s <= t; s++) {
        const float p = zz_bf2f(Spc[(size_t)r * 2048 + s]);
        acc0 += p * zz_bf2f(PZ[(size_t)s * 512 + i0]);
        acc1 += p * zz_bf2f(PZ[(size_t)s * 512 + i0 + 256]);
    }
    Oc[(size_t)t * 512 + i0] = zz_f2bf(acc0);
    Oc[(size_t)t * 512 + i0 + 256] = zz_f2bf(acc1);
}

// ---------------- output projection ----------------
__global__ __launch_bounds__(256) void zk17_oproj(const u16* __restrict__ Oc, const void* __restrict__ Wo,
                                                  unsigned long long kOff, float* __restrict__ y,
                                                  const void* __restrict__ x, int accFlag) {
    const bool isf = zz_isf(x);
    const int t = blockIdx.x;
    const int d0 = threadIdx.x;
    float acc0 = 0.f, acc1 = 0.f;
    for (int i = 0; i < 512; i += 8) {
        f8 w0 = zz_ld8f(Wo, (size_t)d0 * 4096 + (size_t)kOff + i, isf);
        f8 w1 = zz_ld8f(Wo, (size_t)(d0 + 256) * 4096 + (size_t)kOff + i, isf);
#pragma unroll
        for (int u = 0; u < 8; u++) {
            const float of = zz_bf2f(Oc[(size_t)t * 512 + i + u]);
            acc0 += of * w0.v[u];
            acc1 += of * w1.v[u];
        }
    }
    float* p0 = y + (size_t)t * 512 + d0;
    float* p1 = p0 + 256;
    if (accFlag) {
        *p0 += acc0;
        *p1 += acc1;
    } else {
        *p0 = acc0;
        *p1 = acc1;
    }
}

// ---------------- bias + residual + LN; fp32 out if fp32 world, else bf16 ----------------
__global__ __launch_bounds__(256) void zk17_ln(const float* __restrict__ y, const void* __restrict__ x,
                                               unsigned long long rowOff, const void* __restrict__ bo,
                                               const void* __restrict__ ga, const void* __restrict__ be,
                                               void* __restrict__ outbase) {
    const bool isf = zz_isf(x);
    const int wid = threadIdx.x >> 6, lane = threadIdx.x & 63;
    const int row = blockIdx.x * 4 + wid;          // 0..2047 within batch
    const size_t grow = (size_t)rowOff + row;      // global row b*2048 + row
    const int d0 = lane * 8;
    const float* yp = y + (size_t)row * 512 + d0;
    f32x4 a0 = *(const f32x4*)(yp);
    f32x4 a1 = *(const f32x4*)(yp + 4);
    f8 xv = zz_ld8f(x, grow * 512 + d0, isf);
    f8 bov = zz_ld8f(bo, d0, isf);
    float h[8];
#pragma unroll
    for (int j = 0; j < 4; j++) {
        h[j] = a0[j] + bov.v[j] + xv.v[j];
        h[4 + j] = a1[j] + bov.v[4 + j] + xv.v[4 + j];
    }
    float sum = 0.f, sq = 0.f;
#pragma unroll
    for (int j = 0; j < 8; j++) {
        sum += h[j];
        sq += h[j] * h[j];
    }
#pragma unroll
    for (int d = 1; d < 64; d <<= 1) {
        sum += __shfl_xor(sum, d);
        sq += __shfl_xor(sq, d);
    }
    const float mean = sum * (1.f / 512.f);
    const float var = sq * (1.f / 512.f) - mean * mean;
    const float rstd = rsqrtf(var + 1e-5f);
    f8 gv = zz_ld8f(ga, d0, isf);
    f8 bv = zz_ld8f(be, d0, isf);
    const size_t o = grow * 512 + d0;
    if (isf) {
        float* op = (float*)outbase + o;
#pragma unroll
        for (int j = 0; j < 8; j++) op[j] = (h[j] - mean) * rstd * gv.v[j] + bv.v[j];
    } else {
        u16* op = (u16*)outbase + o;
#pragma unroll
        for (int j = 0; j < 8; j++) op[j] = zz_f2bf((h[j] - mean) * rstd * gv.v[j] + bv.v[j]);
    }
}

__global__ __launch_bounds__(256) void zk17_band(float* __restrict__ out, float val) {
    const size_t gid = (size_t)blockIdx.x * 256 + threadIdx.x;
    float* p = out + gid * 8;
#pragma unroll
    for (int j = 0; j < 8; j++) p[j] = val;
}

extern "C" void kernel_launch(void* const* d_in, const int* in_sizes, int n_in, void* d_out,
                              int out_size, void* d_ws, size_t ws_size, hipStream_t stream) {
    if (n_in != 8 || in_sizes[0] != 4194304 || in_sizes[5] != 512) {
        zk17_band<<<dim3(2048), dim3(256), 0, stream>>>((float*)d_out, 16.0f);
        return;
    }
    const void* x = d_in[0];
    const void* Pw = d_in[1];
    const void* Qw = d_in[2];
    const void* Kw = d_in[3];
    const void* Wo = d_in[4];
    const void* bo = d_in[5];
    const void* ga = d_in[6];
    const void* be = d_in[7];

    const size_t TD = (size_t)2048 * 512;
    const size_t WD = (size_t)512 * 512;

    // ws: [pad 512B][QZ|KZ|PZ|Oc bf16, 4*TD elems][y fp32, TD][Spc CH*2048 bf16]
    const size_t need0 = 512 + 8 * TD + 4 * TD;  // 12,583,424 B
    int CH = 0;
    if (d_ws != nullptr && ws_size > need0) {
        size_t room = (ws_size - need0) / 4096;
        for (int c = 2048; c >= 64; c >>= 1)
            if ((size_t)c <= room) { CH = c; break; }
    }
    if (CH == 0) {
        float mb = (float)(ws_size / (1024ull * 1024ull));
        if (mb > 200.f) mb = 200.f;
        zk17_band<<<dim3(2048), dim3(256), 0, stream>>>((float*)d_out, 32.0f * (1.0f + mb));
        return;
    }

    u16* QZ = (u16*)d_ws + 256;
    u16* KZ = QZ + TD;
    u16* PZ = KZ + TD;
    u16* Oc = PZ + TD;
    float* y = (float*)(Oc + TD);
    u16* Spc = (u16*)(y + TD);

    for (int b = 0; b < 4; b++) {
        const unsigned long long xOff = (unsigned long long)b * TD;
        for (int h = 0; h < 8; h++) {
            const unsigned long long wOff = (unsigned long long)h * WD;
            zk17_proj<<<dim3(2048, 3), dim3(256), 0, stream>>>(x, xOff, Qw, Kw, Pw, wOff, QZ, KZ, PZ);
            for (int t0 = 0; t0 < 2048; t0 += CH) {
                zk17_qk<<<dim3(CH), dim3(256), 0, stream>>>(QZ, KZ, Spc, t0);
                zk17_sm<<<dim3(CH / 4), dim3(256), 0, stream>>>(Spc, t0);
                zk17_pv<<<dim3(CH), dim3(256), 0, stream>>>(Spc, PZ, Oc, t0);
            }
            zk17_oproj<<<dim3(2048), dim3(256), 0, stream>>>(Oc, Wo, (unsigned long long)h * 512, y, x,
                                                             (h == 0) ? 0 : 1);
        }
        zk17_ln<<<dim3(512), dim3(256), 0, stream>>>(y, x, (unsigned long long)b * 2048, bo, ga, be,
                                                     d_out);
    }
}

// Round 19
// 3053.401 us; speedup vs baseline: 24.1686x; 24.1686x over previous
//
#include <hip/hip_runtime.h>

typedef unsigned short u16;
typedef __attribute__((ext_vector_type(8))) short bf16x8;
typedef __attribute__((ext_vector_type(8))) unsigned short u16x8;
typedef __attribute__((ext_vector_type(4))) float f32x4;

__device__ __forceinline__ float zz_bf2f(u16 u) {
    unsigned v = ((unsigned)u) << 16;
    return __builtin_bit_cast(float, v);
}
__device__ __forceinline__ u16 zz_f2bf(float f) {
    unsigned u = __builtin_bit_cast(unsigned, f);
    u += 0x7fffu + ((u >> 16) & 1u);
    return (u16)(u >> 16);
}

// Load 8 contiguous elements at element-index idx as bf16 bits (converting if fp32 source).
__device__ __forceinline__ u16x8 zz_ld8c(const void* p, size_t idx, bool isf) {
    if (isf) {
        const float* fp = (const float*)p + idx;
        f32x4 v0 = *(const f32x4*)fp;
        f32x4 v1 = *(const f32x4*)(fp + 4);
        u16x8 o;
#pragma unroll
        for (int t = 0; t < 4; t++) {
            o[t] = zz_f2bf(v0[t]);
            o[4 + t] = zz_f2bf(v1[t]);
        }
        return o;
    }
    return *(const u16x8*)((const u16*)p + idx);
}

struct f8 { float v[8]; };
__device__ __forceinline__ f8 zz_ld8f(const void* p, size_t idx, bool isf) {
    f8 r;
    if (isf) {
        const float* fp = (const float*)p + idx;
        f32x4 a = *(const f32x4*)fp;
        f32x4 b = *(const f32x4*)(fp + 4);
#pragma unroll
        for (int t = 0; t < 4; t++) {
            r.v[t] = a[t];
            r.v[4 + t] = b[t];
        }
    } else {
        const u16* up = (const u16*)p + idx;
#pragma unroll
        for (int t = 0; t < 8; t++) r.v[t] = zz_bf2f(up[t]);
    }
    return r;
}

__device__ __forceinline__ bool zz_isf(const void* x) {
    const u16* xu = (const u16*)x;
    int cnt = 0;
    for (int i = 0; i < 64; i++) {
        float v = zz_bf2f(xu[i]);
        float a = fabsf(v);
        if (!(a <= 1e8f) || (v != 0.f && a < 1e-8f)) cnt++;
    }
    return cnt >= 16;
}

#define MFMA16(a, b, c) __builtin_amdgcn_mfma_f32_16x16x32_bf16((a), (b), (c), 0, 0, 0)

// ---------------- m92-style 128x128-tile GEMM core: acc += A(tile) * B(tile)^T ----------------
__device__ __forceinline__ void zz_gemm128(const void* __restrict__ A, size_t aOff, bool a32,
                                           const void* __restrict__ B, size_t bOff, bool b32,
                                           int K, int lda, int ldb, int tm, int tn,
                                           u16* As, u16* Bs, f32x4 acc[4][4]) {
    const int tid = threadIdx.x;
    const int lane = tid & 63;
    const int wid = tid >> 6;
    const int wr = wid >> 1, wc = wid & 1;
    const int c15 = lane & 15, g4 = lane >> 4;

    const int rA = tid >> 2;          // 0..63
    const int cA = (tid & 3) << 3;    // 0,8,16,24
    const size_t iA0 = aOff + (size_t)(tm * 128 + rA) * lda + cA;
    const size_t iA1 = iA0 + (size_t)64 * lda;
    const size_t iB0 = bOff + (size_t)(tn * 128 + rA) * ldb + cA;
    const size_t iB1 = iB0 + (size_t)64 * ldb;
    u16* sA0 = As + rA * 32 + cA;
    u16* sA1 = sA0 + 64 * 32;
    u16* sB0 = Bs + rA * 32 + cA;
    u16* sB1 = sB0 + 64 * 32;

    for (int k0 = 0; k0 < K; k0 += 32) {
        u16x8 a0 = zz_ld8c(A, iA0 + k0, a32);
        u16x8 a1 = zz_ld8c(A, iA1 + k0, a32);
        u16x8 b0 = zz_ld8c(B, iB0 + k0, b32);
        u16x8 b1 = zz_ld8c(B, iB1 + k0, b32);
        __syncthreads();
        *(u16x8*)sA0 = a0;
        *(u16x8*)sA1 = a1;
        *(u16x8*)sB0 = b0;
        *(u16x8*)sB1 = b1;
        __syncthreads();
        bf16x8 af[4], bfr[4];
#pragma unroll
        for (int mf = 0; mf < 4; mf++)
            af[mf] = *(const bf16x8*)(As + (wr * 64 + mf * 16 + c15) * 32 + g4 * 8);
#pragma unroll
        for (int nf = 0; nf < 4; nf++)
            bfr[nf] = *(const bf16x8*)(Bs + (wc * 64 + nf * 16 + c15) * 32 + g4 * 8);
#pragma unroll
        for (int mf = 0; mf < 4; mf++)
#pragma unroll
            for (int nf = 0; nf < 4; nf++) acc[mf][nf] = MFMA16(af[mf], bfr[nf], acc[mf][nf]);
    }
}

// ---------------- projections for head group [g0, g0+G) of one batch ----------------
// part 0: QZ[g] = x_b @ Qw[h]^T (2048x512); part 1: KZ[g]; part 2: Vt[g] = Pw[h] @ x_b^T (512x2048)
__global__ __launch_bounds__(256) void zk18_proj(const void* __restrict__ x, unsigned long long xOff,
                                                 const void* __restrict__ Qw, const void* __restrict__ Kw,
                                                 const void* __restrict__ Pw, int g0, int G,
                                                 u16* __restrict__ QZ, u16* __restrict__ KZ,
                                                 u16* __restrict__ Vt) {
    __shared__ u16 As[128 * 32];
    __shared__ u16 Bs[128 * 32];
    const bool isf = zz_isf(x);
    const size_t TD = (size_t)2048 * 512;
    const size_t WD = (size_t)512 * 512;
    const int seg = blockIdx.y;
    const int part = seg / G;
    const int g = seg - part * G;
    const int head = g0 + g;
    const int bx = blockIdx.x;

    f32x4 acc[4][4];
    const f32x4 zf = {0.f, 0.f, 0.f, 0.f};
#pragma unroll
    for (int i = 0; i < 4; i++)
#pragma unroll
        for (int j = 0; j < 4; j++) acc[i][j] = zf;

    const int lane = threadIdx.x & 63;
    const int wid = threadIdx.x >> 6;
    const int wr = wid >> 1, wc = wid & 1;
    const int c15 = lane & 15, g4 = lane >> 4;

    if (part < 2) {
        const void* W = (part == 0) ? Qw : Kw;
        u16* C = ((part == 0) ? QZ : KZ) + (size_t)g * TD;
        const int tm = bx >> 2, tn = bx & 3;  // 2048x512
        zz_gemm128(x, xOff, isf, W, (size_t)head * WD, isf, 512, 512, 512, tm, tn, As, Bs, acc);
#pragma unroll
        for (int mf = 0; mf < 4; mf++)
#pragma unroll
            for (int nf = 0; nf < 4; nf++) {
                const int row0 = tm * 128 + wr * 64 + mf * 16 + g4 * 4;
                const int col = tn * 128 + wc * 64 + nf * 16 + c15;
#pragma unroll
                for (int r = 0; r < 4; r++) C[(size_t)(row0 + r) * 512 + col] = zz_f2bf(acc[mf][nf][r]);
            }
    } else {
        u16* C = Vt + (size_t)g * TD;
        const int tm = bx >> 4, tn = bx & 15;  // 512x2048
        zz_gemm128(Pw, (size_t)head * WD, isf, x, xOff, isf, 512, 512, 512, tm, tn, As, Bs, acc);
#pragma unroll
        for (int mf = 0; mf < 4; mf++)
#pragma unroll
            for (int nf = 0; nf < 4; nf++) {
                const int row0 = tm * 128 + wr * 64 + mf * 16 + g4 * 4;
                const int col = tn * 128 + wc * 64 + nf * 16 + c15;
#pragma unroll
                for (int r = 0; r < 4; r++) C[(size_t)(row0 + r) * 2048 + col] = zz_f2bf(acc[mf][nf][r]);
            }
    }
}

// ---------------- flash attention: 1 wave = 16 q-rows x D=512; head hl = blockIdx.y ----------------
__global__ __launch_bounds__(64) void zk18_flash(const u16* __restrict__ QZ, const u16* __restrict__ KZ,
                                                 const u16* __restrict__ Vt, u16* __restrict__ Oc,
                                                 int ldo) {
    __shared__ u16 Plds[16 * 32];
    const int lane = threadIdx.x & 63;
    const int c = lane & 15, g = lane >> 4;
    const int hl = blockIdx.y;
    const int q0 = blockIdx.x * 16;
    const int T = 2048;
    const size_t TD = (size_t)T * 512;
    const float SCL2 = 0.06375826722338107f;  // (1/sqrt(512)) * log2(e)

    bf16x8 qf[16];
    const u16* Qp = QZ + hl * TD + (size_t)(q0 + c) * 512 + g * 8;
#pragma unroll
    for (int ks = 0; ks < 16; ks++) qf[ks] = *(const bf16x8*)(Qp + ks * 32);

    const f32x4 zf = {0.f, 0.f, 0.f, 0.f};
    f32x4 o[32];
#pragma unroll
    for (int nf = 0; nf < 32; nf++) o[nf] = zf;
    float mR[4], lR[4];
#pragma unroll
    for (int r = 0; r < 4; r++) { mR[r] = -1e30f; lR[r] = 0.f; }

    for (int s0 = 0; s0 < q0 + 16; s0 += 32) {
        f32x4 sa0 = zf, sa1 = zf;
        const u16* Kp0 = KZ + hl * TD + (size_t)(s0 + c) * 512 + g * 8;
        const u16* Kp1 = Kp0 + 16 * 512;
#pragma unroll
        for (int ks = 0; ks < 16; ks++) {
            bf16x8 k0v = *(const bf16x8*)(Kp0 + ks * 32);
            bf16x8 k1v = *(const bf16x8*)(Kp1 + ks * 32);
            sa0 = MFMA16(qf[ks], k0v, sa0);
            sa1 = MFMA16(qf[ks], k1v, sa1);
        }
        float fac[4], p0[4], p1[4];
#pragma unroll
        for (int r = 0; r < 4; r++) {
            const int t = q0 + g * 4 + r;
            float v0 = (s0 + c <= t) ? sa0[r] * SCL2 : -INFINITY;
            float v1 = (s0 + 16 + c <= t) ? sa1[r] * SCL2 : -INFINITY;
            float rm = fmaxf(v0, v1);
#pragma unroll
            for (int d = 1; d < 16; d <<= 1) rm = fmaxf(rm, __shfl_xor(rm, d));
            const float mN = fmaxf(mR[r], rm);
            fac[r] = exp2f(mR[r] - mN);
            mR[r] = mN;
            p0[r] = exp2f(v0 - mN);
            p1[r] = exp2f(v1 - mN);
            float rs = p0[r] + p1[r];
#pragma unroll
            for (int d = 1; d < 16; d <<= 1) rs += __shfl_xor(rs, d);
            lR[r] = lR[r] * fac[r] + rs;
            Plds[(g * 4 + r) * 32 + c] = zz_f2bf(p0[r]);
            Plds[(g * 4 + r) * 32 + 16 + c] = zz_f2bf(p1[r]);
        }
        const f32x4 facv = {fac[0], fac[1], fac[2], fac[3]};
#pragma unroll
        for (int nf = 0; nf < 32; nf++) o[nf] *= facv;
        __syncthreads();
        const bf16x8 pa = *(const bf16x8*)(Plds + c * 32 + g * 8);
        __syncthreads();
        const u16* Vp = Vt + hl * TD + (size_t)c * T + s0 + g * 8;
#pragma unroll
        for (int nf = 0; nf < 32; nf++) {
            bf16x8 vf = *(const bf16x8*)(Vp + (size_t)nf * 16 * T);
            o[nf] = MFMA16(pa, vf, o[nf]);
        }
    }

    const f32x4 inv = {1.f / lR[0], 1.f / lR[1], 1.f / lR[2], 1.f / lR[3]};
#pragma unroll
    for (int nf = 0; nf < 32; nf++) {
        f32x4 ov = o[nf] * inv;
#pragma unroll
        for (int r = 0; r < 4; r++) {
            const int t = q0 + g * 4 + r;
            Oc[(size_t)t * ldo + hl * 512 + nf * 16 + c] = zz_f2bf(ov[r]);
        }
    }
}

// ---------------- output projection: y (+)= Oc(2048 x G*512) @ Wo[:, g0*512..]^T ----------------
__global__ __launch_bounds__(256) void zk18_oproj(const u16* __restrict__ Oc, const void* __restrict__ Wo,
                                                  int g0, int G, float* __restrict__ y,
                                                  const void* __restrict__ x, int accFlag) {
    __shared__ u16 As[128 * 32];
    __shared__ u16 Bs[128 * 32];
    const bool isf = zz_isf(x);
    const int bx = blockIdx.x;
    const int tm = bx >> 2, tn = bx & 3;

    f32x4 acc[4][4];
    const f32x4 zf = {0.f, 0.f, 0.f, 0.f};
#pragma unroll
    for (int i = 0; i < 4; i++)
#pragma unroll
        for (int j = 0; j < 4; j++) acc[i][j] = zf;

    zz_gemm128(Oc, 0, false, Wo, (size_t)g0 * 512, isf, G * 512, G * 512, 4096, tm, tn, As, Bs, acc);

    const int lane = threadIdx.x & 63;
    const int wid = threadIdx.x >> 6;
    const int wr = wid >> 1, wc = wid & 1;
    const int c15 = lane & 15, g4 = lane >> 4;
#pragma unroll
    for (int mf = 0; mf < 4; mf++)
#pragma unroll
        for (int nf = 0; nf < 4; nf++) {
            const int row0 = tm * 128 + wr * 64 + mf * 16 + g4 * 4;
            const int col = tn * 128 + wc * 64 + nf * 16 + c15;
#pragma unroll
            for (int r = 0; r < 4; r++) {
                float* p = y + (size_t)(row0 + r) * 512 + col;
                *p = accFlag ? (*p + acc[mf][nf][r]) : acc[mf][nf][r];
            }
        }
}

// ---------------- bias + residual + LN; fp32 out (bf16 fallback) ----------------
__global__ __launch_bounds__(256) void zk18_ln(const float* __restrict__ y, const void* __restrict__ x,
                                               unsigned long long rowOff, const void* __restrict__ bo,
                                               const void* __restrict__ ga, const void* __restrict__ be,
                                               void* __restrict__ outbase) {
    const bool isf = zz_isf(x);
    const int wid = threadIdx.x >> 6, lane = threadIdx.x & 63;
    const int row = blockIdx.x * 4 + wid;
    const size_t grow = (size_t)rowOff + row;
    const int d0 = lane * 8;
    const float* yp = y + (size_t)row * 512 + d0;
    f32x4 a0 = *(const f32x4*)(yp);
    f32x4 a1 = *(const f32x4*)(yp + 4);
    f8 xv = zz_ld8f(x, grow * 512 + d0, isf);
    f8 bov = zz_ld8f(bo, d0, isf);
    float h[8];
#pragma unroll
    for (int j = 0; j < 4; j++) {
        h[j] = a0[j] + bov.v[j] + xv.v[j];
        h[4 + j] = a1[j] + bov.v[4 + j] + xv.v[4 + j];
    }
    float sum = 0.f, sq = 0.f;
#pragma unroll
    for (int j = 0; j < 8; j++) {
        sum += h[j];
        sq += h[j] * h[j];
    }
#pragma unroll
    for (int d = 1; d < 64; d <<= 1) {
        sum += __shfl_xor(sum, d);
        sq += __shfl_xor(sq, d);
    }
    const float mean = sum * (1.f / 512.f);
    const float var = sq * (1.f / 512.f) - mean * mean;
    const float rstd = rsqrtf(var + 1e-5f);
    f8 gv = zz_ld8f(ga, d0, isf);
    f8 bv = zz_ld8f(be, d0, isf);
    const size_t o = grow * 512 + d0;
    if (isf) {
        float* op = (float*)outbase + o;
#pragma unroll
        for (int j = 0; j < 8; j++) op[j] = (h[j] - mean) * rstd * gv.v[j] + bv.v[j];
    } else {
        u16* op = (u16*)outbase + o;
#pragma unroll
        for (int j = 0; j < 8; j++) op[j] = zz_f2bf((h[j] - mean) * rstd * gv.v[j] + bv.v[j]);
    }
}

__global__ __launch_bounds__(256) void zk18_band(float* __restrict__ out, float val) {
    const size_t gid = (size_t)blockIdx.x * 256 + threadIdx.x;
    float* p = out + gid * 8;
#pragma unroll
    for (int j = 0; j < 8; j++) p[j] = val;
}

extern "C" void kernel_launch(void* const* d_in, const int* in_sizes, int n_in, void* d_out,
                              int out_size, void* d_ws, size_t ws_size, hipStream_t stream) {
    if (n_in != 8 || in_sizes[0] != 4194304 || in_sizes[5] != 512) {
        zk18_band<<<dim3(2048), dim3(256), 0, stream>>>((float*)d_out, 16.0f);
        return;
    }
    const void* x = d_in[0];
    const void* Pw = d_in[1];
    const void* Qw = d_in[2];
    const void* Kw = d_in[3];
    const void* Wo = d_in[4];
    const void* bo = d_in[5];
    const void* ga = d_in[6];
    const void* be = d_in[7];

    const size_t TD = (size_t)2048 * 512;

    // ws (bytes): 512 pad + [QZ|KZ|Vt|Oc bf16: 4*G*TD*2] + [y fp32: TD*4]
    // need(G) = G*8MB + 4MB + 512.  G=1 -> 12.0 MB (known to fit from r17).
    int G = 1;
    for (int g = 8; g >= 1; g >>= 1) {
        size_t need = 512 + (size_t)g * 8 * TD + 4 * TD;
        if (ws_size >= need) { G = g; break; }
    }

    u16* QZ = (u16*)d_ws + 256;
    u16* KZ = QZ + (size_t)G * TD;
    u16* Vt = KZ + (size_t)G * TD;
    u16* Oc = Vt + (size_t)G * TD;          // 2048 x (G*512) bf16
    float* y = (float*)(Oc + (size_t)G * TD);

    for (int b = 0; b < 4; b++) {
        const unsigned long long xOff = (unsigned long long)b * TD;
        for (int g0 = 0; g0 < 8; g0 += G) {
            zk18_proj<<<dim3(64, 3 * G), dim3(256), 0, stream>>>(x, xOff, Qw, Kw, Pw, g0, G,
                                                                 QZ, KZ, Vt);
            zk18_flash<<<dim3(128, G), dim3(64), 0, stream>>>(QZ, KZ, Vt, Oc, G * 512);
            zk18_oproj<<<dim3(64), dim3(256), 0, stream>>>(Oc, Wo, g0, G, y, x, (g0 == 0) ? 0 : 1);
        }
        zk18_ln<<<dim3(512), dim3(256), 0, stream>>>(y, x, (unsigned long long)b * 2048, bo, ga, be,
                                                     d_out);
    }
}

// Round 20
// 2196.010 us; speedup vs baseline: 33.6048x; 1.3904x over previous
//
#include <hip/hip_runtime.h>

typedef unsigned short u16;
typedef __attribute__((ext_vector_type(8))) short bf16x8;
typedef __attribute__((ext_vector_type(8))) unsigned short u16x8;
typedef __attribute__((ext_vector_type(4))) float f32x4;

__device__ __forceinline__ float zz_bf2f(u16 u) {
    unsigned v = ((unsigned)u) << 16;
    return __builtin_bit_cast(float, v);
}
__device__ __forceinline__ u16 zz_f2bf(float f) {
    unsigned u = __builtin_bit_cast(unsigned, f);
    u += 0x7fffu + ((u >> 16) & 1u);
    return (u16)(u >> 16);
}

__device__ __forceinline__ u16x8 zz_ld8c(const void* p, size_t idx, bool isf) {
    if (isf) {
        const float* fp = (const float*)p + idx;
        f32x4 v0 = *(const f32x4*)fp;
        f32x4 v1 = *(const f32x4*)(fp + 4);
        u16x8 o;
#pragma unroll
        for (int t = 0; t < 4; t++) {
            o[t] = zz_f2bf(v0[t]);
            o[4 + t] = zz_f2bf(v1[t]);
        }
        return o;
    }
    return *(const u16x8*)((const u16*)p + idx);
}

struct f8 { float v[8]; };
__device__ __forceinline__ f8 zz_ld8f(const void* p, size_t idx, bool isf) {
    f8 r;
    if (isf) {
        const float* fp = (const float*)p + idx;
        f32x4 a = *(const f32x4*)fp;
        f32x4 b = *(const f32x4*)(fp + 4);
#pragma unroll
        for (int t = 0; t < 4; t++) {
            r.v[t] = a[t];
            r.v[4 + t] = b[t];
        }
    } else {
        const u16* up = (const u16*)p + idx;
#pragma unroll
        for (int t = 0; t < 8; t++) r.v[t] = zz_bf2f(up[t]);
    }
    return r;
}

__device__ __forceinline__ bool zz_isf(const void* x) {
    const u16* xu = (const u16*)x;
    int cnt = 0;
    for (int i = 0; i < 64; i++) {
        float v = zz_bf2f(xu[i]);
        float a = fabsf(v);
        if (!(a <= 1e8f) || (v != 0.f && a < 1e-8f)) cnt++;
    }
    return cnt >= 16;
}

#define MFMA16(a, b, c) __builtin_amdgcn_mfma_f32_16x16x32_bf16((a), (b), (c), 0, 0, 0)

// ---------------- m92-style 128x128-tile GEMM core ----------------
__device__ __forceinline__ void zz_gemm128(const void* __restrict__ A, size_t aOff, bool a32,
                                           const void* __restrict__ B, size_t bOff, bool b32,
                                           int K, int lda, int ldb, int tm, int tn,
                                           u16* As, u16* Bs, f32x4 acc[4][4]) {
    const int tid = threadIdx.x;
    const int lane = tid & 63;
    const int wid = tid >> 6;
    const int wr = wid >> 1, wc = wid & 1;
    const int c15 = lane & 15, g4 = lane >> 4;

    const int rA = tid >> 2;
    const int cA = (tid & 3) << 3;
    const size_t iA0 = aOff + (size_t)(tm * 128 + rA) * lda + cA;
    const size_t iA1 = iA0 + (size_t)64 * lda;
    const size_t iB0 = bOff + (size_t)(tn * 128 + rA) * ldb + cA;
    const size_t iB1 = iB0 + (size_t)64 * ldb;
    u16* sA0 = As + rA * 32 + cA;
    u16* sA1 = sA0 + 64 * 32;
    u16* sB0 = Bs + rA * 32 + cA;
    u16* sB1 = sB0 + 64 * 32;

    for (int k0 = 0; k0 < K; k0 += 32) {
        u16x8 a0 = zz_ld8c(A, iA0 + k0, a32);
        u16x8 a1 = zz_ld8c(A, iA1 + k0, a32);
        u16x8 b0 = zz_ld8c(B, iB0 + k0, b32);
        u16x8 b1 = zz_ld8c(B, iB1 + k0, b32);
        __syncthreads();
        *(u16x8*)sA0 = a0;
        *(u16x8*)sA1 = a1;
        *(u16x8*)sB0 = b0;
        *(u16x8*)sB1 = b1;
        __syncthreads();
        bf16x8 af[4], bfr[4];
#pragma unroll
        for (int mf = 0; mf < 4; mf++)
            af[mf] = *(const bf16x8*)(As + (wr * 64 + mf * 16 + c15) * 32 + g4 * 8);
#pragma unroll
        for (int nf = 0; nf < 4; nf++)
            bfr[nf] = *(const bf16x8*)(Bs + (wc * 64 + nf * 16 + c15) * 32 + g4 * 8);
#pragma unroll
        for (int mf = 0; mf < 4; mf++)
#pragma unroll
            for (int nf = 0; nf < 4; nf++) acc[mf][nf] = MFMA16(af[mf], bfr[nf], acc[mf][nf]);
    }
}

// ---------------- projections, NB batches x 8 heads in one launch ----------------
// seg = blockIdx.y: part = seg>>3 (0:QZ 1:KZ 2:Vt), h = seg&7; lb = blockIdx.z.
__global__ __launch_bounds__(256) void zk19_proj(const void* __restrict__ x, int b0,
                                                 const void* __restrict__ Qw, const void* __restrict__ Kw,
                                                 const void* __restrict__ Pw,
                                                 u16* __restrict__ QZ, u16* __restrict__ KZ,
                                                 u16* __restrict__ Vt) {
    __shared__ u16 As[128 * 32];
    __shared__ u16 Bs[128 * 32];
    const bool isf = zz_isf(x);
    const size_t TD = (size_t)2048 * 512;
    const size_t WD = (size_t)512 * 512;
    const int lb = blockIdx.z;
    const int seg = blockIdx.y;
    const int part = seg >> 3;
    const int h = seg & 7;
    const int slot = lb * 8 + h;
    const size_t xOff = (size_t)(b0 + lb) * TD;
    const int bx = blockIdx.x;

    f32x4 acc[4][4];
    const f32x4 zf = {0.f, 0.f, 0.f, 0.f};
#pragma unroll
    for (int i = 0; i < 4; i++)
#pragma unroll
        for (int j = 0; j < 4; j++) acc[i][j] = zf;

    const int lane = threadIdx.x & 63;
    const int wid = threadIdx.x >> 6;
    const int wr = wid >> 1, wc = wid & 1;
    const int c15 = lane & 15, g4 = lane >> 4;

    if (part < 2) {
        const void* W = (part == 0) ? Qw : Kw;
        u16* C = ((part == 0) ? QZ : KZ) + (size_t)slot * TD;
        const int tm = bx >> 2, tn = bx & 3;  // 2048x512
        zz_gemm128(x, xOff, isf, W, (size_t)h * WD, isf, 512, 512, 512, tm, tn, As, Bs, acc);
#pragma unroll
        for (int mf = 0; mf < 4; mf++)
#pragma unroll
            for (int nf = 0; nf < 4; nf++) {
                const int row0 = tm * 128 + wr * 64 + mf * 16 + g4 * 4;
                const int col = tn * 128 + wc * 64 + nf * 16 + c15;
#pragma unroll
                for (int r = 0; r < 4; r++) C[(size_t)(row0 + r) * 512 + col] = zz_f2bf(acc[mf][nf][r]);
            }
    } else {
        u16* C = Vt + (size_t)slot * TD;
        const int tm = bx >> 4, tn = bx & 15;  // 512x2048
        zz_gemm128(Pw, (size_t)h * WD, isf, x, xOff, isf, 512, 512, 512, tm, tn, As, Bs, acc);
#pragma unroll
        for (int mf = 0; mf < 4; mf++)
#pragma unroll
            for (int nf = 0; nf < 4; nf++) {
                const int row0 = tm * 128 + wr * 64 + mf * 16 + g4 * 4;
                const int col = tn * 128 + wc * 64 + nf * 16 + c15;
#pragma unroll
                for (int r = 0; r < 4; r++) C[(size_t)(row0 + r) * 2048 + col] = zz_f2bf(acc[mf][nf][r]);
            }
    }
}

// ---------------- flash: 1 wave = 16 q-rows x D=512; h = blockIdx.y, lb = blockIdx.z ----------------
// q-tiles launched in REVERSE order (largest causal workload first) to shrink the tail.
__global__ __launch_bounds__(64) void zk19_flash(const u16* __restrict__ QZ, const u16* __restrict__ KZ,
                                                 const u16* __restrict__ Vt, u16* __restrict__ Oc) {
    __shared__ u16 Plds[16 * 32];
    const int lane = threadIdx.x & 63;
    const int c = lane & 15, g = lane >> 4;
    const int lb = blockIdx.z;
    const int h = blockIdx.y;
    const int slot = lb * 8 + h;
    const int q0 = (127 - blockIdx.x) * 16;
    const int T = 2048;
    const size_t TD = (size_t)T * 512;
    const float SCL2 = 0.06375826722338107f;  // (1/sqrt(512)) * log2(e)

    bf16x8 qf[16];
    const u16* Qp = QZ + (size_t)slot * TD + (size_t)(q0 + c) * 512 + g * 8;
#pragma unroll
    for (int ks = 0; ks < 16; ks++) qf[ks] = *(const bf16x8*)(Qp + ks * 32);

    const f32x4 zf = {0.f, 0.f, 0.f, 0.f};
    f32x4 o[32];
#pragma unroll
    for (int nf = 0; nf < 32; nf++) o[nf] = zf;
    float mR[4], lR[4];
#pragma unroll
    for (int r = 0; r < 4; r++) { mR[r] = -1e30f; lR[r] = 0.f; }

    for (int s0 = 0; s0 < q0 + 16; s0 += 32) {
        f32x4 sa0 = zf, sa1 = zf;
        const u16* Kp0 = KZ + (size_t)slot * TD + (size_t)(s0 + c) * 512 + g * 8;
        const u16* Kp1 = Kp0 + 16 * 512;
#pragma unroll
        for (int ks = 0; ks < 16; ks++) {
            bf16x8 k0v = *(const bf16x8*)(Kp0 + ks * 32);
            bf16x8 k1v = *(const bf16x8*)(Kp1 + ks * 32);
            sa0 = MFMA16(qf[ks], k0v, sa0);
            sa1 = MFMA16(qf[ks], k1v, sa1);
        }
        float fac[4], p0[4], p1[4];
#pragma unroll
        for (int r = 0; r < 4; r++) {
            const int t = q0 + g * 4 + r;
            float v0 = (s0 + c <= t) ? sa0[r] * SCL2 : -INFINITY;
            float v1 = (s0 + 16 + c <= t) ? sa1[r] * SCL2 : -INFINITY;
            float rm = fmaxf(v0, v1);
#pragma unroll
            for (int d = 1; d < 16; d <<= 1) rm = fmaxf(rm, __shfl_xor(rm, d));
            const float mN = fmaxf(mR[r], rm);
            fac[r] = exp2f(mR[r] - mN);
            mR[r] = mN;
            p0[r] = exp2f(v0 - mN);
            p1[r] = exp2f(v1 - mN);
            float rs = p0[r] + p1[r];
#pragma unroll
            for (int d = 1; d < 16; d <<= 1) rs += __shfl_xor(rs, d);
            lR[r] = lR[r] * fac[r] + rs;
            Plds[(g * 4 + r) * 32 + c] = zz_f2bf(p0[r]);
            Plds[(g * 4 + r) * 32 + 16 + c] = zz_f2bf(p1[r]);
        }
        const f32x4 facv = {fac[0], fac[1], fac[2], fac[3]};
#pragma unroll
        for (int nf = 0; nf < 32; nf++) o[nf] *= facv;
        __syncthreads();
        const bf16x8 pa = *(const bf16x8*)(Plds + c * 32 + g * 8);
        __syncthreads();
        const u16* Vp = Vt + (size_t)slot * TD + (size_t)c * T + s0 + g * 8;
#pragma unroll
        for (int nf = 0; nf < 32; nf++) {
            bf16x8 vf = *(const bf16x8*)(Vp + (size_t)nf * 16 * T);
            o[nf] = MFMA16(pa, vf, o[nf]);
        }
    }

    const f32x4 inv = {1.f / lR[0], 1.f / lR[1], 1.f / lR[2], 1.f / lR[3]};
#pragma unroll
    for (int nf = 0; nf < 32; nf++) {
        f32x4 ov = o[nf] * inv;
#pragma unroll
        for (int r = 0; r < 4; r++) {
            const int t = q0 + g * 4 + r;
            Oc[(size_t)(lb * 2048 + t) * 4096 + h * 512 + nf * 16 + c] = zz_f2bf(ov[r]);
        }
    }
}

// ---------------- output projection: y[lb] = Oc[lb](2048x4096) @ Wo^T, fp32 ----------------
__global__ __launch_bounds__(256) void zk19_oproj(const u16* __restrict__ Oc, const void* __restrict__ Wo,
                                                  float* __restrict__ y, const void* __restrict__ x) {
    __shared__ u16 As[128 * 32];
    __shared__ u16 Bs[128 * 32];
    const bool isf = zz_isf(x);
    const int lb = blockIdx.y;
    const int bx = blockIdx.x;
    const int tm = bx >> 2, tn = bx & 3;  // 2048 x 512

    f32x4 acc[4][4];
    const f32x4 zf = {0.f, 0.f, 0.f, 0.f};
#pragma unroll
    for (int i = 0; i < 4; i++)
#pragma unroll
        for (int j = 0; j < 4; j++) acc[i][j] = zf;

    zz_gemm128(Oc, (size_t)lb * 2048 * 4096, false, Wo, 0, isf, 4096, 4096, 4096, tm, tn, As, Bs, acc);

    const int lane = threadIdx.x & 63;
    const int wid = threadIdx.x >> 6;
    const int wr = wid >> 1, wc = wid & 1;
    const int c15 = lane & 15, g4 = lane >> 4;
    float* yb = y + (size_t)lb * 2048 * 512;
#pragma unroll
    for (int mf = 0; mf < 4; mf++)
#pragma unroll
        for (int nf = 0; nf < 4; nf++) {
            const int row0 = tm * 128 + wr * 64 + mf * 16 + g4 * 4;
            const int col = tn * 128 + wc * 64 + nf * 16 + c15;
#pragma unroll
            for (int r = 0; r < 4; r++) yb[(size_t)(row0 + r) * 512 + col] = acc[mf][nf][r];
        }
}

// ---------------- bias + residual + LN; fp32 out (bf16 fallback) ----------------
__global__ __launch_bounds__(256) void zk19_ln(const float* __restrict__ y, const void* __restrict__ x,
                                               int b0, const void* __restrict__ bo,
                                               const void* __restrict__ ga, const void* __restrict__ be,
                                               void* __restrict__ outbase) {
    const bool isf = zz_isf(x);
    const int lb = blockIdx.y;
    const int wid = threadIdx.x >> 6, lane = threadIdx.x & 63;
    const int row = blockIdx.x * 4 + wid;            // 0..2047 within batch
    const size_t grow = (size_t)(b0 + lb) * 2048 + row;
    const int d0 = lane * 8;
    const float* yp = y + ((size_t)lb * 2048 + row) * 512 + d0;
    f32x4 a0 = *(const f32x4*)(yp);
    f32x4 a1 = *(const f32x4*)(yp + 4);
    f8 xv = zz_ld8f(x, grow * 512 + d0, isf);
    f8 bov = zz_ld8f(bo, d0, isf);
    float h[8];
#pragma unroll
    for (int j = 0; j < 4; j++) {
        h[j] = a0[j] + bov.v[j] + xv.v[j];
        h[4 + j] = a1[j] + bov.v[4 + j] + xv.v[4 + j];
    }
    float sum = 0.f, sq = 0.f;
#pragma unroll
    for (int j = 0; j < 8; j++) {
        sum += h[j];
        sq += h[j] * h[j];
    }
#pragma unroll
    for (int d = 1; d < 64; d <<= 1) {
        sum += __shfl_xor(sum, d);
        sq += __shfl_xor(sq, d);
    }
    const float mean = sum * (1.f / 512.f);
    const float var = sq * (1.f / 512.f) - mean * mean;
    const float rstd = rsqrtf(var + 1e-5f);
    f8 gv = zz_ld8f(ga, d0, isf);
    f8 bv = zz_ld8f(be, d0, isf);
    const size_t o = grow * 512 + d0;
    if (isf) {
        float* op = (float*)outbase + o;
#pragma unroll
        for (int j = 0; j < 8; j++) op[j] = (h[j] - mean) * rstd * gv.v[j] + bv.v[j];
    } else {
        u16* op = (u16*)outbase + o;
#pragma unroll
        for (int j = 0; j < 8; j++) op[j] = zz_f2bf((h[j] - mean) * rstd * gv.v[j] + bv.v[j]);
    }
}

__global__ __launch_bounds__(256) void zk19_band(float* __restrict__ out, float val) {
    const size_t gid = (size_t)blockIdx.x * 256 + threadIdx.x;
    float* p = out + gid * 8;
#pragma unroll
    for (int j = 0; j < 8; j++) p[j] = val;
}

extern "C" void kernel_launch(void* const* d_in, const int* in_sizes, int n_in, void* d_out,
                              int out_size, void* d_ws, size_t ws_size, hipStream_t stream) {
    if (n_in != 8 || in_sizes[0] != 4194304 || in_sizes[5] != 512) {
        zk19_band<<<dim3(2048), dim3(256), 0, stream>>>((float*)d_out, 16.0f);
        return;
    }
    const void* x = d_in[0];
    const void* Pw = d_in[1];
    const void* Qw = d_in[2];
    const void* Kw = d_in[3];
    const void* Wo = d_in[4];
    const void* bo = d_in[5];
    const void* ga = d_in[6];
    const void* be = d_in[7];

    const size_t TD = (size_t)2048 * 512;

    // per-batch ws cost: QZ/KZ/Vt (3 x 8 x TD x 2B = 48MB) + Oc (2048x4096x2B = 16MB) + y (4MB)
    // need(NB) = 512 + NB * 68 MB.  r18 proved ws >= 68.5 MB (G=8 ran).
    auto need = [&](int nb) -> size_t {
        return 512 + (size_t)nb * (3 * 8 * TD * 2 + (size_t)2048 * 4096 * 2 + TD * 4);
    };
    int NB = 1;
    if (ws_size >= need(4)) NB = 4;
    else if (ws_size >= need(2)) NB = 2;

    u16* QZ = (u16*)d_ws + 256;
    u16* KZ = QZ + (size_t)NB * 8 * TD;
    u16* Vt = KZ + (size_t)NB * 8 * TD;
    u16* Oc = Vt + (size_t)NB * 8 * TD;                    // NB x 2048 x 4096 bf16
    float* y = (float*)(Oc + (size_t)NB * 2048 * 4096);    // NB x TD fp32

    for (int b0 = 0; b0 < 4; b0 += NB) {
        zk19_proj<<<dim3(64, 24, NB), dim3(256), 0, stream>>>(x, b0, Qw, Kw, Pw, QZ, KZ, Vt);
        zk19_flash<<<dim3(128, 8, NB), dim3(64), 0, stream>>>(QZ, KZ, Vt, Oc);
        zk19_oproj<<<dim3(64, NB), dim3(256), 0, stream>>>(Oc, Wo, y, x);
        zk19_ln<<<dim3(512, NB), dim3(256), 0, stream>>>(y, x, b0, bo, ga, be, d_out);
    }
}